// Round 2
// baseline (62.887 us; speedup 1.0000x reference)
//
#include <hip/hip_runtime.h>
#include <math.h>

// Problem constants
#define E      4096
#define BATCH  8
#define COLB   256            // columns per block (64 lanes x float4)

// ---------------------------------------------------------------------------
// Kernel A: split-K partial GEMM for  yin @ (w + alpha*hebb)
//   partial[kBlock][b][col] = sum_{k in kBlock} yin[b][k] * (w[k][col] + alpha[k][col]*hebb[k][col])
// Deterministic: fixed partitioning, fixed reduction order, no atomics.
// Templated on KB (k-rows per block). 4 waves split KB; each wave does KB/4 k's.
// Inner loop batches 4 k-iterations of loads (12 float4 in flight) for MLP.
// ---------------------------------------------------------------------------
template <int KB>
__global__ __launch_bounds__(256, 4) void partial_gemm_kernel(
    const float* __restrict__ yin,
    const float* __restrict__ hebb,
    const float* __restrict__ w,
    const float* __restrict__ alpha,
    float* __restrict__ partial)          // [E/KB][BATCH][E]
{
    __shared__ __align__(16) float s_yin[BATCH * KB];
    __shared__ __align__(16) float s_red[4 * BATCH * COLB];  // 32 KiB

    const int t    = threadIdx.x;
    const int lane = t & 63;
    const int wave = t >> 6;              // 0..3
    const int colBlock = blockIdx.x;      // 0..15
    const int kBlock   = blockIdx.y;      // 0..E/KB-1

    // Stage yin[b][kBlock*KB .. +KB) into LDS (float4 per thread).
    {
        const int nf4 = BATCH * KB / 4;   // 128 (KB=64) or 256 (KB=128)
        for (int i = t; i < nf4; i += 256) {
            const int b   = (i * 4) / KB;
            const int off = (i * 4) % KB;
            const float4 v = *reinterpret_cast<const float4*>(
                yin + (size_t)b * E + (size_t)kBlock * KB + off);
            *reinterpret_cast<float4*>(&s_yin[b * KB + off]) = v;
        }
    }
    __syncthreads();

    const int col0 = colBlock * COLB + lane * 4;

    float4 acc[BATCH];
#pragma unroll
    for (int b = 0; b < BATCH; ++b) acc[b] = make_float4(0.f, 0.f, 0.f, 0.f);

    const int kLocal0 = wave * (KB / 4);  // KB/4 k's per wave

    // Groups of 4 k's: issue all 12 float4 loads, then consume.
#pragma unroll
    for (int g = 0; g < KB / 16; ++g) {
        float4 w4[4], a4[4], h4[4];
#pragma unroll
        for (int u = 0; u < 4; ++u) {
            const size_t row = (size_t)(kBlock * KB + kLocal0 + g * 4 + u) * E + col0;
            w4[u] = *reinterpret_cast<const float4*>(w + row);
            a4[u] = *reinterpret_cast<const float4*>(alpha + row);
            h4[u] = *reinterpret_cast<const float4*>(hebb + row);
        }
#pragma unroll
        for (int u = 0; u < 4; ++u) {
            float4 m;
            m.x = w4[u].x + a4[u].x * h4[u].x;
            m.y = w4[u].y + a4[u].y * h4[u].y;
            m.z = w4[u].z + a4[u].z * h4[u].z;
            m.w = w4[u].w + a4[u].w * h4[u].w;
            const int kL = kLocal0 + g * 4 + u;
#pragma unroll
            for (int b = 0; b < BATCH; ++b) {
                const float yv = s_yin[b * KB + kL];
                acc[b].x = fmaf(yv, m.x, acc[b].x);
                acc[b].y = fmaf(yv, m.y, acc[b].y);
                acc[b].z = fmaf(yv, m.z, acc[b].z);
                acc[b].w = fmaf(yv, m.w, acc[b].w);
            }
        }
    }

    // Store per-wave accumulators: layout s_red[wave][b][COLB]
#pragma unroll
    for (int b = 0; b < BATCH; ++b) {
        *reinterpret_cast<float4*>(&s_red[(wave * BATCH + b) * COLB + lane * 4]) = acc[b];
    }
    __syncthreads();

    // Reduce 4 waves -> partial.  col = t (coalesced LDS + global).
#pragma unroll
    for (int b = 0; b < BATCH; ++b) {
        const int col = t;
        const float s = s_red[(0 * BATCH + b) * COLB + col]
                      + s_red[(1 * BATCH + b) * COLB + col]
                      + s_red[(2 * BATCH + b) * COLB + col]
                      + s_red[(3 * BATCH + b) * COLB + col];
        partial[((size_t)kBlock * BATCH + b) * E + colBlock * COLB + col] = s;
    }
}

// ---------------------------------------------------------------------------
// Kernel B: yout[b][j] = tanh(input[b][j] + sum_kb partial[kb][b][j])
// ---------------------------------------------------------------------------
template <int NKB>
__global__ __launch_bounds__(256) void finalize_yout_kernel(
    const float* __restrict__ input,
    const float* __restrict__ partial,
    float* __restrict__ yout)
{
    const int idx = blockIdx.x * 256 + threadIdx.x;   // 0..32767
    const int b = idx >> 12;
    const int j = idx & (E - 1);

    float s = input[idx];
#pragma unroll 8
    for (int kb = 0; kb < NKB; ++kb)
        s += partial[((size_t)kb * BATCH + b) * E + j];

    yout[idx] = tanhf(s);
}

// ---------------------------------------------------------------------------
// Kernel C: hebb_new = (1-eta)*hebb + eta * outer(yin[0], yout[0])
// ---------------------------------------------------------------------------
__global__ __launch_bounds__(256) void hebb_update_kernel(
    const float* __restrict__ hebb,
    const float* __restrict__ yin,
    const float* __restrict__ yout,       // d_out row 0 (already written)
    const float* __restrict__ eta_p,
    float* __restrict__ hebb_out)
{
    const float eta  = eta_p[0];
    const float keep = 1.0f - eta;

    const size_t N4 = (size_t)E * E / 4;  // 4,194,304 float4's
    const size_t stride = (size_t)gridDim.x * blockDim.x;

    for (size_t i4 = (size_t)blockIdx.x * blockDim.x + threadIdx.x; i4 < N4; i4 += stride) {
        const size_t base = i4 * 4;
        const int row = (int)(base >> 12);          // i index
        const int jcol = (int)(base & (E - 1));     // j index (multiple of 4)

        const float y0 = yin[row] * eta;            // eta * yin[0][row]
        const float4 h  = *reinterpret_cast<const float4*>(hebb + base);
        const float4 yo = *reinterpret_cast<const float4*>(yout + jcol);

        float4 r;
        r.x = fmaf(y0, yo.x, keep * h.x);
        r.y = fmaf(y0, yo.y, keep * h.y);
        r.z = fmaf(y0, yo.z, keep * h.z);
        r.w = fmaf(y0, yo.w, keep * h.w);

        *reinterpret_cast<float4*>(hebb_out + base) = r;
    }
}

// ---------------------------------------------------------------------------
extern "C" void kernel_launch(void* const* d_in, const int* in_sizes, int n_in,
                              void* d_out, int out_size, void* d_ws, size_t ws_size,
                              hipStream_t stream) {
    const float* input = (const float*)d_in[0];   // [8, 4096]
    const float* yin   = (const float*)d_in[1];   // [8, 4096]
    const float* hebb  = (const float*)d_in[2];   // [4096, 4096]
    const float* w     = (const float*)d_in[3];   // [4096, 4096]
    const float* alpha = (const float*)d_in[4];   // [4096, 4096]
    const float* eta   = (const float*)d_in[5];   // [1]

    float* out      = (float*)d_out;
    float* yout     = out;                               // 8*4096 floats
    float* hebb_out = out + (size_t)BATCH * E;           // 4096*4096 floats
    float* partial  = (float*)d_ws;

    const size_t need64 = (size_t)(E / 64) * BATCH * E * sizeof(float);  // 8 MiB

    if (ws_size >= need64) {
        // KB=64: 1024 blocks, 4 blocks/CU fully co-resident.
        dim3 gridA(E / COLB, E / 64);   // 16 x 64
        partial_gemm_kernel<64><<<gridA, 256, 0, stream>>>(yin, hebb, w, alpha, partial);
        finalize_yout_kernel<64><<<(BATCH * E) / 256, 256, 0, stream>>>(input, partial, yout);
    } else {
        // Fallback KB=128 (4 MiB partial, known to fit).
        dim3 gridA(E / COLB, E / 128); // 16 x 32
        partial_gemm_kernel<128><<<gridA, 256, 0, stream>>>(yin, hebb, w, alpha, partial);
        finalize_yout_kernel<32><<<(BATCH * E) / 256, 256, 0, stream>>>(input, partial, yout);
    }

    hebb_update_kernel<<<2048, 256, 0, stream>>>(hebb, yin, yout, eta, hebb_out);
}